// Round 5
// baseline (152.929 us; speedup 1.0000x reference)
//
#include <hip/hip_runtime.h>

constexpr int BS  = 32;
constexpr int D   = 2048;
constexpr float P = 0.5f;

constexpr int TPB = 256;            // threads per block
constexpr int NPT = 4;              // n-elements per thread (float4)
constexpr int NB  = D / (TPB*NPT);  // 2 n-blocks
constexpr int KC  = 64;             // k-chunks
constexpr int KCH = D / KC;         // 32 k rows per chunk
constexpr int BPB = 4;              // batches per block (in-register weight reuse)
constexpr int BG  = BS / BPB;       // 8 batch-groups
constexpr int DV  = D / 4;          // float4 per row

typedef float floatx4 __attribute__((ext_vector_type(4)));

__global__ __launch_bounds__(TPB) void dropconnect_kernel(
    const float* __restrict__ x,      // (BS, D)
    const float* __restrict__ weight, // (D, D)   axes (k, n)
    const float* __restrict__ bias,   // (D,)
    const float* __restrict__ u_w,    // (BS, D, D) axes (b, k, n)
    const float* __restrict__ u_b,    // (BS, D)
    float* __restrict__ out)          // (BS, D), pre-zeroed
{
    const int kc  = blockIdx.x;   // 0..63  (flat%8 = kc%8 -> same-XCD weight-tile affinity)
    const int nb  = blockIdx.y;   // 0..1
    const int bg  = blockIdx.z;   // 0..7
    const int tid = threadIdx.x;

    const int n0 = nb * (TPB * NPT) + tid * NPT;
    const int k0 = kc * KCH;
    const int b0 = bg * BPB;

    // Stage x chunks for the BPB batches (block-uniform per k).
    __shared__ float xs[BPB][KCH];
    if (tid < BPB * KCH) {
        const int bb = tid / KCH, kk = tid % KCH;
        xs[bb][kk] = x[(b0 + bb) * D + k0 + kk];
    }
    __syncthreads();

    const floatx4* uw4 = reinterpret_cast<const floatx4*>(u_w);
    const floatx4* w4  = reinterpret_cast<const floatx4*>(weight);

    float acc[BPB][4] = {};

    size_t iw = (size_t)k0 * DV + (n0 >> 2);
    size_t iu[BPB];
#pragma unroll
    for (int bb = 0; bb < BPB; ++bb)
        iu[bb] = ((size_t)(b0 + bb) * D + (size_t)k0) * DV + (n0 >> 2);

#pragma unroll 2
    for (int kk = 0; kk < KCH; ++kk) {
        const floatx4 w = w4[iw];          // loaded ONCE, reused for BPB batches
        iw += DV;
#pragma unroll
        for (int bb = 0; bb < BPB; ++bb) {
            const floatx4 u = uw4[iu[bb]];
            iu[bb] += DV;
            const float xv = xs[bb][kk];
            acc[bb][0] += (u.x <= P) ? xv * w.x : 0.f;
            acc[bb][1] += (u.y <= P) ? xv * w.y : 0.f;
            acc[bb][2] += (u.z <= P) ? xv * w.z : 0.f;
            acc[bb][3] += (u.w <= P) ? xv * w.w : 0.f;
        }
    }

    // Fold the bias term into the kc==0 partial.
    if (kc == 0) {
#pragma unroll
        for (int bb = 0; bb < BPB; ++bb) {
            const floatx4 ub = reinterpret_cast<const floatx4*>(u_b)[((b0 + bb) * D + n0) >> 2];
            const floatx4 bv = reinterpret_cast<const floatx4*>(bias)[n0 >> 2];
            acc[bb][0] += (ub.x <= P) ? bv.x : 0.f;
            acc[bb][1] += (ub.y <= P) ? bv.y : 0.f;
            acc[bb][2] += (ub.z <= P) ? bv.z : 0.f;
            acc[bb][3] += (ub.w <= P) ? bv.w : 0.f;
        }
    }

#pragma unroll
    for (int bb = 0; bb < BPB; ++bb) {
        float* o = out + (size_t)(b0 + bb) * D + n0;
        atomicAdd(o + 0, acc[bb][0]);
        atomicAdd(o + 1, acc[bb][1]);
        atomicAdd(o + 2, acc[bb][2]);
        atomicAdd(o + 3, acc[bb][3]);
    }
}

extern "C" void kernel_launch(void* const* d_in, const int* in_sizes, int n_in,
                              void* d_out, int out_size, void* d_ws, size_t ws_size,
                              hipStream_t stream) {
    const float* x      = (const float*)d_in[0];
    const float* weight = (const float*)d_in[1];
    const float* bias   = (const float*)d_in[2];
    const float* u_w    = (const float*)d_in[3];
    const float* u_b    = (const float*)d_in[4];
    float* out = (float*)d_out;

    // out is poisoned (0xAA) before timing; atomic path needs zeros each call.
    (void)hipMemsetAsync(out, 0, (size_t)out_size * sizeof(float), stream);

    dim3 grid(KC, NB, BG);
    dropconnect_kernel<<<grid, TPB, 0, stream>>>(x, weight, bias, u_w, u_b, out);
}

// Round 6
// 116.587 us; speedup vs baseline: 1.3117x; 1.3117x over previous
//
#include <hip/hip_runtime.h>

constexpr int BS = 32;
constexpr int D  = 2048;
constexpr float P = 0.5f;

constexpr int TPB = 256;            // threads per block
constexpr int NPT = 4;              // n-elements per thread (float4)
constexpr int NB  = D / (TPB*NPT);  // 2 n-blocks
constexpr int KC  = 32;             // k-chunks
constexpr int KCH = D / KC;         // 64 k rows per chunk
constexpr int DV  = D / 4;          // float4 per row

typedef float floatx4 __attribute__((ext_vector_type(4)));

// __launch_bounds__(256, 8): 8 waves/EU -> caps VGPR at 64 so all 8
// blocks/CU (32 waves/CU) are co-resident. Reads (unlike the harness's
// 6.5 TB/s fills, which are fire-and-forget writes) need in-flight bytes
// ~ BW x loaded-latency; 32 waves x ~4KB outstanding covers it, 16 may not.
__global__ __launch_bounds__(TPB, 8) void dropconnect_kernel(
    const float* __restrict__ x,      // (BS, D)
    const float* __restrict__ weight, // (D, D)   axes (k, n)
    const float* __restrict__ bias,   // (D,)
    const float* __restrict__ u_w,    // (BS, D, D) axes (b, k, n)
    const float* __restrict__ u_b,    // (BS, D)
    float* __restrict__ out)          // (BS, D), pre-zeroed
{
    const int kc  = blockIdx.x;   // f%8 = kc%8 -> same-XCD weight-tile affinity
    const int nb  = blockIdx.y;
    const int b   = blockIdx.z;
    const int tid = threadIdx.x;

    const int n0 = nb * (TPB * NPT) + tid * NPT;
    const int k0 = kc * KCH;

    __shared__ float xs[KCH];
    if (tid < KCH) xs[tid] = x[b * D + k0 + tid];
    __syncthreads();

    const floatx4* uw4 = reinterpret_cast<const floatx4*>(u_w);
    const floatx4* w4  = reinterpret_cast<const floatx4*>(weight);

    float acc0 = 0.f, acc1 = 0.f, acc2 = 0.f, acc3 = 0.f;

    size_t iu = ((size_t)b * D + (size_t)k0) * DV + (n0 >> 2);
    size_t iw = (size_t)k0 * DV + (n0 >> 2);

    // unroll 2 (not 4): 16 load-dest VGPRs instead of 32, so the kernel
    // fits the 64-VGPR budget imposed by launch_bounds without spilling.
#pragma unroll 2
    for (int kk = 0; kk < KCH; ++kk) {
        const float xv = xs[kk];
        const floatx4 u = uw4[iu];
        const floatx4 w = w4[iw];
        acc0 += (u.x <= P) ? xv * w.x : 0.f;
        acc1 += (u.y <= P) ? xv * w.y : 0.f;
        acc2 += (u.z <= P) ? xv * w.z : 0.f;
        acc3 += (u.w <= P) ? xv * w.w : 0.f;
        iu += DV;
        iw += DV;
    }

    if (kc == 0) {
        const floatx4 ub = reinterpret_cast<const floatx4*>(u_b)[(b * D + n0) >> 2];
        const floatx4 bv = reinterpret_cast<const floatx4*>(bias)[n0 >> 2];
        acc0 += (ub.x <= P) ? bv.x : 0.f;
        acc1 += (ub.y <= P) ? bv.y : 0.f;
        acc2 += (ub.z <= P) ? bv.z : 0.f;
        acc3 += (ub.w <= P) ? bv.w : 0.f;
    }

    float* o = out + (size_t)b * D + n0;
    atomicAdd(o + 0, acc0);
    atomicAdd(o + 1, acc1);
    atomicAdd(o + 2, acc2);
    atomicAdd(o + 3, acc3);
}

extern "C" void kernel_launch(void* const* d_in, const int* in_sizes, int n_in,
                              void* d_out, int out_size, void* d_ws, size_t ws_size,
                              hipStream_t stream) {
    const float* x      = (const float*)d_in[0];
    const float* weight = (const float*)d_in[1];
    const float* bias   = (const float*)d_in[2];
    const float* u_w    = (const float*)d_in[3];
    const float* u_b    = (const float*)d_in[4];
    float* out = (float*)d_out;

    // out is poisoned (0xAA) before timing; atomic path needs zeros each call.
    (void)hipMemsetAsync(out, 0, (size_t)out_size * sizeof(float), stream);

    dim3 grid(KC, NB, BS);
    dropconnect_kernel<<<grid, TPB, 0, stream>>>(x, weight, bias, u_w, u_b, out);
}